// Round 6
// baseline (1875.753 us; speedup 1.0000x reference)
//
#include <hip/hip_runtime.h>

#define B_ 32
#define N_ 768
#define BN_TOT 24576   // B*N
#define P_ 32
#define C_ 9
#define H_ 64
#define O_ 128
#define EPS_ 1e-5f
#define NBLK 2048

typedef unsigned short u16;

__device__ __forceinline__ float bf2f(u16 u) {
    union { unsigned int i; float f; } v; v.i = ((unsigned int)u) << 16; return v.f;
}
// dtype-agnostic float load: f32 flag chooses fp32 vs bf16 element
__device__ __forceinline__ float ldF(const void* p, long i, bool f32) {
    return f32 ? ((const float*)p)[i] : bf2f(((const u16*)p)[i]);
}
// mask load by mode: 0=int32, 1=float32, 2=bf16(u16), 3=int8
__device__ __forceinline__ float ldMsk(const void* p, long i, int mode) {
    if (mode == 0) return (((const int*)p)[i] != 0) ? 1.f : 0.f;
    if (mode == 1) return (((const float*)p)[i] != 0.f) ? 1.f : 0.f;
    if (mode == 2) return (((const u16*)p)[i] != 0) ? 1.f : 0.f;
    return (((const signed char*)p)[i] != 0) ? 1.f : 0.f;
}

// Workspace float region S layout (floats):
// [0..63] sum1 [64..127] sumsq1 [128..191] sum2 [192..255] sumsq2
// [256..319] sum3 [320..383] sumsq3 [384] cnt
// [512+L*128 .. +63] scaleL, [..+64 .. +127] shiftL  (L=0,1,2)
// [901] mask mode (0..3)
// [910+j] per-input fp32 flag (j = d_in index; float tensors only)

struct DetectArgs { const void* p[14]; int n[14]; };

// ---------- detection: per-tensor float width + mask dtype mode ----------
__global__ void k_detect(DetectArgs a, const void* __restrict__ mask,
                         float* __restrict__ S) {
    int j = threadIdx.x;
    if (j < 14) {
        int jmap = (j == 0) ? 0 : (j + 1);
        const u16* h = (const u16*)a.p[j];
        int E = a.n[j];
        int K = (E < 256) ? E : 256;
        int insane = 0, zeroEven = 0, nzOdd = 0, evens = 0, odds = 0;
        for (int i = 0; i < K; i++) {
            u16 x = h[i];
            int e = (x >> 7) & 0xFF;
            if (e != 0 && (e < 0x60 || e > 0x90)) insane++;
            if ((i & 1) == 0) { evens++; if (x == 0) zeroEven++; }
            else             { odds++;  if (x != 0) nzOdd++; }
        }
        bool f32 = (insane * 8 > K) ||
                   (zeroEven * 5 > evens * 4 && nzOdd * 5 > odds * 4);
        S[910 + jmap] = f32 ? 1.f : 0.f;
    }
    if (j == 14) {
        const unsigned int* w = (const unsigned int*)mask;
        const u16* hm = (const u16*)mask;
        bool ok32 = true, okf32 = true, okbf = true;
        for (int i = 0; i < 64; i++) {
            unsigned int v = w[i];
            if (v > 1u) ok32 = false;
            if (v != 0u && v != 0x3F800000u) okf32 = false;
            u16 x = hm[i];
            if (x != 0 && x != 0x3F80) okbf = false;
        }
        S[901] = ok32 ? 0.f : (okf32 ? 1.f : (okbf ? 2.f : 3.f));
    }
}

// ---------- finalize scale/shift ----------
__global__ void k_finalize(const void* __restrict__ g, const void* __restrict__ b,
                           float* __restrict__ S, int layer, int gi, int bi) {
    int c = threadIdx.x;
    if (c < H_) {
        bool fg = S[910 + gi] > 0.5f, fb = S[910 + bi] > 0.5f;
        float cnt = fmaxf(S[384], 1.f);
        float mean = S[layer * 128 + c] / cnt;
        float var = fmaxf(S[layer * 128 + 64 + c] / cnt - mean * mean, 0.f);
        float sc = ldF(g, c, fg) * rsqrtf(var + EPS_);
        float sh = ldF(b, c, fb) - mean * sc;
        S[512 + layer * 128 + c] = sc;
        S[512 + layer * 128 + 64 + c] = sh;
    }
}

// ---------- stage 1 stats ----------
__global__ __launch_bounds__(256) void pB1_stats1(const void* __restrict__ poly,
                                                  const void* __restrict__ mask,
                                                  const void* __restrict__ Wpre,
                                                  float* __restrict__ S) {
    __shared__ float Wp[576], xs[288], mLds[32], sred[256];
    int t = threadIdx.x, ch = t & 63, pg = t >> 6;
    bool fP = S[910 + 0] > 0.5f, fW = S[910 + 2] > 0.5f;
    int mmode = (int)S[901];
    for (int i = t; i < 576; i += 256) Wp[i] = ldF(Wpre, i, fW);
    float s = 0.f, ss = 0.f, ccnt = 0.f;
    for (int bn = blockIdx.x; bn < BN_TOT; bn += NBLK) {
        __syncthreads();
        for (int i = t; i < 288; i += 256) xs[i] = ldF(poly, (long)bn * 288 + i, fP);
        if (t < 32) mLds[t] = ldMsk(mask, (long)bn * 32 + t, mmode);
        __syncthreads();
        if (t == 0) { float c2 = 0.f; for (int p = 0; p < 32; p++) c2 += mLds[p]; ccnt += c2; }
        #pragma unroll
        for (int j = 0; j < 8; j++) {
            int p = pg * 8 + j;
            float hv = 0.f;
            #pragma unroll
            for (int c = 0; c < 9; c++) hv += Wp[ch * 9 + c] * xs[p * 9 + c];
            float m = mLds[p];
            s += hv * m; ss += hv * hv * m;
        }
    }
    __syncthreads();
    sred[t] = s; __syncthreads();
    if (t < 64) atomicAdd(&S[t], sred[t] + sred[t + 64] + sred[t + 128] + sred[t + 192]);
    __syncthreads();
    sred[t] = ss; __syncthreads();
    if (t < 64) atomicAdd(&S[64 + t], sred[t] + sred[t + 64] + sred[t + 128] + sred[t + 192]);
    if (t == 0) atomicAdd(&S[384], ccnt);
}

// ---------- stage 2 stats (recompute feat) ----------
__global__ __launch_bounds__(256) void pB3_stats2(const void* __restrict__ poly,
                                                  const void* __restrict__ mask,
                                                  const void* __restrict__ Wpre,
                                                  const void* __restrict__ W1g,
                                                  float* __restrict__ S) {
    __shared__ float Wp[576], xs[288], mLds[32], sred[256], feat[2048], pooled[64];
    __shared__ float W1p[4096];   // W1p[k*64+ch] = W1[ch][64+k]
    int t = threadIdx.x, ch = t & 63, pg = t >> 6;
    bool fP = S[910 + 0] > 0.5f, fW = S[910 + 2] > 0.5f, fW1 = S[910 + 5] > 0.5f;
    int mmode = (int)S[901];
    for (int i = t; i < 576; i += 256) Wp[i] = ldF(Wpre, i, fW);
    for (int i = t; i < 4096; i += 256) {
        int k = i >> 6, c2 = i & 63;
        W1p[k * 64 + c2] = ldF(W1g, c2 * 128 + 64 + k, fW1);
    }
    float wr[64];
    #pragma unroll
    for (int k = 0; k < 64; k++) wr[k] = ldF(W1g, ch * 128 + k, fW1);
    float sc1 = S[512 + ch], sh1 = S[576 + ch];
    float s = 0.f, ss = 0.f;
    for (int bn = blockIdx.x; bn < BN_TOT; bn += NBLK) {
        __syncthreads();
        for (int i = t; i < 288; i += 256) xs[i] = ldF(poly, (long)bn * 288 + i, fP);
        if (t < 32) mLds[t] = ldMsk(mask, (long)bn * 32 + t, mmode);
        __syncthreads();
        #pragma unroll
        for (int j = 0; j < 8; j++) {
            int p = pg * 8 + j;
            float hv = 0.f;
            #pragma unroll
            for (int c = 0; c < 9; c++) hv += Wp[ch * 9 + c] * xs[p * 9 + c];
            feat[p * 64 + ch] = fmaxf(hv * sc1 + sh1, 0.f) * mLds[p];
        }
        __syncthreads();
        if (t < 64) {
            float mx = 0.f;
            #pragma unroll
            for (int p = 0; p < 32; p++) mx = fmaxf(mx, feat[p * 64 + t]);
            pooled[t] = mx;
        }
        __syncthreads();
        float qv = 0.f;
        #pragma unroll
        for (int k = 0; k < 64; k++) qv += W1p[k * 64 + ch] * pooled[k];
        #pragma unroll
        for (int j = 0; j < 8; j++) {
            int p = pg * 8 + j;
            const float* fp = &feat[p * 64];
            float hv = qv;
            #pragma unroll
            for (int k = 0; k < 64; k++) hv += wr[k] * fp[k];
            float m = mLds[p];
            s += hv * m; ss += hv * hv * m;
        }
    }
    __syncthreads();
    sred[t] = s; __syncthreads();
    if (t < 64) atomicAdd(&S[128 + t], sred[t] + sred[t + 64] + sred[t + 128] + sred[t + 192]);
    __syncthreads();
    sred[t] = ss; __syncthreads();
    if (t < 64) atomicAdd(&S[192 + t], sred[t] + sred[t + 64] + sred[t + 128] + sred[t + 192]);
}

// ---------- stage 3 stats (recompute feat, h1) ----------
__global__ __launch_bounds__(256) void pB5_stats3(const void* __restrict__ poly,
                                                  const void* __restrict__ mask,
                                                  const void* __restrict__ Wpre,
                                                  const void* __restrict__ W1g,
                                                  const void* __restrict__ W2g,
                                                  float* __restrict__ S) {
    __shared__ float Wp[576], xs[288], mLds[32], sred[256], feat[2048], gbuf[2048], pooled[64];
    __shared__ float W1p[4096];
    int t = threadIdx.x, ch = t & 63, pg = t >> 6;
    bool fP = S[910 + 0] > 0.5f, fW = S[910 + 2] > 0.5f;
    bool fW1 = S[910 + 5] > 0.5f, fW2 = S[910 + 8] > 0.5f;
    int mmode = (int)S[901];
    for (int i = t; i < 576; i += 256) Wp[i] = ldF(Wpre, i, fW);
    for (int i = t; i < 4096; i += 256) {
        int k = i >> 6, c2 = i & 63;
        W1p[k * 64 + c2] = ldF(W1g, c2 * 128 + 64 + k, fW1);
    }
    float wr1[64], wr2[64];
    #pragma unroll
    for (int k = 0; k < 64; k++) wr1[k] = ldF(W1g, ch * 128 + k, fW1);
    #pragma unroll
    for (int k = 0; k < 64; k++) wr2[k] = ldF(W2g, ch * 64 + k, fW2);
    float sc1 = S[512 + ch], sh1 = S[576 + ch], sc2 = S[640 + ch], sh2 = S[704 + ch];
    float s = 0.f, ss = 0.f;
    for (int bn = blockIdx.x; bn < BN_TOT; bn += NBLK) {
        __syncthreads();
        for (int i = t; i < 288; i += 256) xs[i] = ldF(poly, (long)bn * 288 + i, fP);
        if (t < 32) mLds[t] = ldMsk(mask, (long)bn * 32 + t, mmode);
        __syncthreads();
        #pragma unroll
        for (int j = 0; j < 8; j++) {
            int p = pg * 8 + j;
            float hv = 0.f;
            #pragma unroll
            for (int c = 0; c < 9; c++) hv += Wp[ch * 9 + c] * xs[p * 9 + c];
            feat[p * 64 + ch] = fmaxf(hv * sc1 + sh1, 0.f) * mLds[p];
        }
        __syncthreads();
        if (t < 64) {
            float mx = 0.f;
            #pragma unroll
            for (int p = 0; p < 32; p++) mx = fmaxf(mx, feat[p * 64 + t]);
            pooled[t] = mx;
        }
        __syncthreads();
        float qv = 0.f;
        #pragma unroll
        for (int k = 0; k < 64; k++) qv += W1p[k * 64 + ch] * pooled[k];
        #pragma unroll
        for (int j = 0; j < 8; j++) {
            int p = pg * 8 + j;
            const float* fp = &feat[p * 64];
            float hv = qv;
            #pragma unroll
            for (int k = 0; k < 64; k++) hv += wr1[k] * fp[k];
            gbuf[p * 64 + ch] = fmaxf(hv * sc2 + sh2, 0.f) * mLds[p];
        }
        __syncthreads();
        #pragma unroll
        for (int j = 0; j < 8; j++) {
            int p = pg * 8 + j;
            const float* gp = &gbuf[p * 64];
            float hv = 0.f;
            #pragma unroll
            for (int k = 0; k < 64; k++) hv += wr2[k] * gp[k];
            float m = mLds[p];
            s += hv * m; ss += hv * hv * m;
        }
    }
    __syncthreads();
    sred[t] = s; __syncthreads();
    if (t < 64) atomicAdd(&S[256 + t], sred[t] + sred[t + 64] + sred[t + 128] + sred[t + 192]);
    __syncthreads();
    sred[t] = ss; __syncthreads();
    if (t < 64) atomicAdd(&S[320 + t], sred[t] + sred[t + 64] + sred[t + 128] + sred[t + 192]);
}

// ---------- final: recompute everything + out MLP; fp32 output ----------
__global__ __launch_bounds__(256) void pB7_out(const void* __restrict__ poly,
                                               const void* __restrict__ mask,
                                               const void* __restrict__ Wpre,
                                               const void* __restrict__ W1g,
                                               const void* __restrict__ W2g,
                                               const void* __restrict__ Wo1,
                                               const void* __restrict__ bo1,
                                               const void* __restrict__ Wo2,
                                               const void* __restrict__ bo2,
                                               const float* __restrict__ S,
                                               float* __restrict__ out) {
    __shared__ float Wp[576], xs[288], mLds[32], feat[2048], gbuf[2048], pooled[64];
    __shared__ float arr[256], ovec[64], y1[64];
    __shared__ float W1p[4096], Wo1T[4096], Wo2T[8192];
    __shared__ float vflag;
    int t = threadIdx.x, ch = t & 63, pg = t >> 6;
    bool fP = S[910 + 0] > 0.5f, fW = S[910 + 2] > 0.5f;
    bool fW1 = S[910 + 5] > 0.5f, fW2 = S[910 + 8] > 0.5f;
    bool fO1 = S[910 + 11] > 0.5f, fB1 = S[910 + 12] > 0.5f;
    bool fO2 = S[910 + 13] > 0.5f, fB2 = S[910 + 14] > 0.5f;
    int mmode = (int)S[901];
    for (int i = t; i < 576; i += 256) Wp[i] = ldF(Wpre, i, fW);
    for (int i = t; i < 4096; i += 256) {
        int k = i >> 6, c2 = i & 63;
        W1p[k * 64 + c2] = ldF(W1g, c2 * 128 + 64 + k, fW1);
    }
    for (int i = t; i < 4096; i += 256) { int h = i >> 6, k = i & 63; Wo1T[k * 64 + h] = ldF(Wo1, i, fO1); }
    for (int i = t; i < 8192; i += 256) { int o = i >> 6, k = i & 63; Wo2T[k * 128 + o] = ldF(Wo2, i, fO2); }
    float wr1[64], wr2[64];
    #pragma unroll
    for (int k = 0; k < 64; k++) wr1[k] = ldF(W1g, ch * 128 + k, fW1);
    #pragma unroll
    for (int k = 0; k < 64; k++) wr2[k] = ldF(W2g, ch * 64 + k, fW2);
    float sc1 = S[512 + ch], sh1 = S[576 + ch], sc2 = S[640 + ch], sh2 = S[704 + ch];
    float sc3 = S[768 + ch], sh3 = S[832 + ch];
    float bo1v = (t < 64) ? ldF(bo1, t, fB1) : 0.f;
    float bo2v = (t < 128) ? ldF(bo2, t, fB2) : 0.f;
    for (int bn = blockIdx.x; bn < BN_TOT; bn += NBLK) {
        __syncthreads();
        for (int i = t; i < 288; i += 256) xs[i] = ldF(poly, (long)bn * 288 + i, fP);
        if (t < 32) mLds[t] = ldMsk(mask, (long)bn * 32 + t, mmode);
        __syncthreads();
        if (t == 0) { float v = 0.f; for (int p = 0; p < 32; p++) v = fmaxf(v, mLds[p]); vflag = v; }
        #pragma unroll
        for (int j = 0; j < 8; j++) {
            int p = pg * 8 + j;
            float hv = 0.f;
            #pragma unroll
            for (int c = 0; c < 9; c++) hv += Wp[ch * 9 + c] * xs[p * 9 + c];
            feat[p * 64 + ch] = fmaxf(hv * sc1 + sh1, 0.f) * mLds[p];
        }
        __syncthreads();
        if (t < 64) {
            float mx = 0.f;
            #pragma unroll
            for (int p = 0; p < 32; p++) mx = fmaxf(mx, feat[p * 64 + t]);
            pooled[t] = mx;
        }
        __syncthreads();
        float qv = 0.f;
        #pragma unroll
        for (int k = 0; k < 64; k++) qv += W1p[k * 64 + ch] * pooled[k];
        #pragma unroll
        for (int j = 0; j < 8; j++) {
            int p = pg * 8 + j;
            const float* fp = &feat[p * 64];
            float hv = qv;
            #pragma unroll
            for (int k = 0; k < 64; k++) hv += wr1[k] * fp[k];
            gbuf[p * 64 + ch] = fmaxf(hv * sc2 + sh2, 0.f) * mLds[p];
        }
        __syncthreads();
        float pmax = 0.f;
        #pragma unroll
        for (int j = 0; j < 8; j++) {
            int p = pg * 8 + j;
            const float* gp = &gbuf[p * 64];
            float hv = 0.f;
            #pragma unroll
            for (int k = 0; k < 64; k++) hv += wr2[k] * gp[k];
            hv = fmaxf(hv * sc3 + sh3, 0.f) * mLds[p];
            pmax = fmaxf(pmax, hv);
        }
        arr[pg * 64 + ch] = pmax;
        __syncthreads();
        if (t < 64) ovec[t] = fmaxf(fmaxf(arr[t], arr[64 + t]), fmaxf(arr[128 + t], arr[192 + t]));
        __syncthreads();
        if (t < 64) {
            float acc = bo1v;
            #pragma unroll
            for (int k = 0; k < 64; k++) acc += Wo1T[k * 64 + t] * ovec[k];
            y1[t] = fmaxf(acc, 0.f);
        }
        __syncthreads();
        if (t < 128) {
            float acc = bo2v;
            #pragma unroll
            for (int k = 0; k < 64; k++) acc += Wo2T[k * 128 + t] * y1[k];
            out[(size_t)bn * 128 + t] = acc * vflag;   // fp32 output
        }
    }
}

extern "C" void kernel_launch(void* const* d_in, const int* in_sizes, int n_in,
                              void* d_out, int out_size, void* d_ws, size_t ws_size,
                              hipStream_t stream) {
    const void* poly = d_in[0];
    const void* mask = d_in[1];
    const void* Wpre = d_in[2];
    const void* gpre = d_in[3];
    const void* bpre = d_in[4];
    const void* W1   = d_in[5];
    const void* g1   = d_in[6];
    const void* b1   = d_in[7];
    const void* W2   = d_in[8];
    const void* g2   = d_in[9];
    const void* b2   = d_in[10];
    const void* Wo1  = d_in[11];
    const void* bo1  = d_in[12];
    const void* Wo2  = d_in[13];
    const void* bo2  = d_in[14];

    float* S = (float*)d_ws;
    float* out = (float*)d_out;

    DetectArgs da;
    {
        int fidx[14] = {0, 2, 3, 4, 5, 6, 7, 8, 9, 10, 11, 12, 13, 14};
        for (int j = 0; j < 14; j++) { da.p[j] = d_in[fidx[j]]; da.n[j] = in_sizes[fidx[j]]; }
    }

    hipMemsetAsync(S, 0, 512 * sizeof(float), stream);  // zero stats sums + cnt
    k_detect<<<1, 64, 0, stream>>>(da, mask, S);
    pB1_stats1<<<NBLK, 256, 0, stream>>>(poly, mask, Wpre, S);
    k_finalize<<<1, 64, 0, stream>>>(gpre, bpre, S, 0, 3, 4);
    pB3_stats2<<<NBLK, 256, 0, stream>>>(poly, mask, Wpre, W1, S);
    k_finalize<<<1, 64, 0, stream>>>(g1, b1, S, 1, 6, 7);
    pB5_stats3<<<NBLK, 256, 0, stream>>>(poly, mask, Wpre, W1, W2, S);
    k_finalize<<<1, 64, 0, stream>>>(g2, b2, S, 2, 9, 10);
    pB7_out<<<NBLK, 256, 0, stream>>>(poly, mask, Wpre, W1, W2, Wo1, bo1, Wo2, bo2, S, out);
}

// Round 7
// 1144.091 us; speedup vs baseline: 1.6395x; 1.6395x over previous
//
#include <hip/hip_runtime.h>

#define BN_TOT 24576   // B*N
#define EPS_ 1e-5f
#define NBLK 2048
#define TOTW (NBLK * 4)   // total waves; 24576/8192 = 3 polylines per wave (exact)

typedef float v4f __attribute__((ext_vector_type(4)));

__device__ __forceinline__ v4f ld4(const float* p) { return *(const v4f*)p; }
__device__ __forceinline__ void st4(float* p, v4f v) { *(v4f*)p = v; }

// Workspace S (floats):
// [0..63] sum1 [64..127] sumsq1 [128..191] sum2 [192..255] sumsq2
// [256..319] sum3 [320..383] sumsq3 [384] cnt
// [512+L*128 .. +63] scaleL, [+64 .. +127] shiftL  (L=0,1,2)

__global__ void k_finalize(const float* __restrict__ g, const float* __restrict__ b,
                           float* __restrict__ S, int layer) {
    int c = threadIdx.x;
    if (c < 64) {
        float cnt = fmaxf(S[384], 1.f);
        float mean = S[layer * 128 + c] / cnt;
        float var = fmaxf(S[layer * 128 + 64 + c] / cnt - mean * mean, 0.f);
        float sc = g[c] * rsqrtf(var + EPS_);
        float sh = b[c] - mean * sc;
        S[512 + layer * 128 + c] = sc;
        S[512 + layer * 128 + 64 + c] = sh;
    }
}

// One wave owns one polyline at a time. Lane tile: 4 points x 8 channels.
// lane = pg*8+cg; pg in [0,8): points 4pg..4pg+3; cg in [0,8): chans 8cg..8cg+7.
// actT layout: act[wv][k*36 + p]  (stride 36 -> conflict-free b128 reads over p).
// Weight LDS layout: WT[k*64 + ch] (b128 over ch, 2-way bank alias = free).
template<int NSTAGE, bool DO_OUT>
__global__ __launch_bounds__(256) void pipe_k(
    const float* __restrict__ poly, const int* __restrict__ mask,
    const float* __restrict__ Wpre, const float* __restrict__ W1,
    const float* __restrict__ W2, const float* __restrict__ Wo1,
    const float* __restrict__ bo1f, const float* __restrict__ Wo2,
    const float* __restrict__ bo2f,
    float* __restrict__ S, float* __restrict__ out)
{
    __shared__ __align__(16) float WpT[9 * 64];
    __shared__ __align__(16) float W1aT[64 * 64];
    __shared__ __align__(16) float W1pT[64 * 64];
    __shared__ __align__(16) float W2T[64 * 64];
    __shared__ __align__(16) float Wo1T[64 * 64];
    __shared__ __align__(16) float Wo2T[64 * 128];
    __shared__ __align__(16) float act[4][64 * 36];
    __shared__ __align__(16) float xT[4][9 * 36];
    __shared__ float pbuf[4][64];
    __shared__ float red_s[4][64], red_ss[4][64], red_c[4];

    const int t = threadIdx.x, wv = t >> 6, lane = t & 63;
    const int pg = lane >> 3, cg = lane & 7;

    // ---- stage weights into LDS (transposed) ----
    for (int i = t; i < 576; i += 256) { int c = i >> 6, ch = i & 63; WpT[i] = Wpre[ch * 9 + c]; }
    if constexpr (NSTAGE >= 2) {
        for (int i = t; i < 4096; i += 256) {
            int k = i >> 6, ch = i & 63;
            W1aT[i] = W1[ch * 128 + k];
            W1pT[i] = W1[ch * 128 + 64 + k];
        }
    }
    if constexpr (NSTAGE >= 3) {
        for (int i = t; i < 4096; i += 256) { int k = i >> 6, ch = i & 63; W2T[i] = W2[ch * 64 + k]; }
    }
    if constexpr (DO_OUT) {
        for (int i = t; i < 4096; i += 256) { int k = i >> 6, ch = i & 63; Wo1T[i] = Wo1[ch * 64 + k]; }
        for (int i = t; i < 8192; i += 256) { int k = i >> 7, o = i & 127; Wo2T[i] = Wo2[o * 64 + k]; }
    }
    __syncthreads();

    // ---- per-lane BN constants (ch = 8cg+j) ----
    float sc1[8], sh1[8], sc2[8], sh2[8], sc3[8], sh3[8];
    if constexpr (NSTAGE >= 2)
        for (int j = 0; j < 8; j++) { sc1[j] = S[512 + 8 * cg + j]; sh1[j] = S[576 + 8 * cg + j]; }
    if constexpr (NSTAGE >= 3)
        for (int j = 0; j < 8; j++) { sc2[j] = S[640 + 8 * cg + j]; sh2[j] = S[704 + 8 * cg + j]; }
    if constexpr (DO_OUT)
        for (int j = 0; j < 8; j++) { sc3[j] = S[768 + 8 * cg + j]; sh3[j] = S[832 + 8 * cg + j]; }
    float bo1v = 0.f, bo2a = 0.f, bo2b = 0.f;
    if constexpr (DO_OUT) { bo1v = bo1f[lane]; bo2a = bo2f[lane]; bo2b = bo2f[64 + lane]; }

    float sp[8] = {0}, ssp[8] = {0};
    float cntp = 0.f;

    const int wgid = blockIdx.x * 4 + wv;
    for (int bn = wgid; bn < BN_TOT; bn += TOTW) {   // exactly 3 iters for every wave
        __syncthreads();   // recycle per-wave LDS safely across iterations

        // mask: lanes 0..31 load, distribute via shuffle
        float mv = (lane < 32 && mask[bn * 32 + lane] != 0) ? 1.f : 0.f;
        float m[4];
        #pragma unroll
        for (int i = 0; i < 4; i++) m[i] = __shfl(mv, 4 * pg + i);

        // x load + transpose: xT[c*36 + p]
        const float* xg = poly + (size_t)bn * 288;
        for (int e = lane; e < 288; e += 64) {
            float v = xg[e];
            int p = e / 9, c = e - 9 * p;
            xT[wv][c * 36 + p] = v;
        }
        __builtin_amdgcn_wave_barrier();

        // ---- stage 1: h_pre = W_pre @ x  (K=9) ----
        float a1[4][8];
        #pragma unroll
        for (int i = 0; i < 4; i++)
            #pragma unroll
            for (int j = 0; j < 8; j++) a1[i][j] = 0.f;
        #pragma unroll
        for (int k = 0; k < 9; k++) {
            v4f av = ld4(&xT[wv][k * 36 + 4 * pg]);
            v4f w0 = ld4(&WpT[k * 64 + 8 * cg]);
            v4f w1 = ld4(&WpT[k * 64 + 8 * cg + 4]);
            #pragma unroll
            for (int i = 0; i < 4; i++)
                #pragma unroll
                for (int j = 0; j < 4; j++) {
                    a1[i][j] += av[i] * w0[j];
                    a1[i][4 + j] += av[i] * w1[j];
                }
        }

        if constexpr (NSTAGE == 1) {
            #pragma unroll
            for (int i = 0; i < 4; i++)
                #pragma unroll
                for (int j = 0; j < 8; j++) {
                    float hv = a1[i][j];
                    sp[j] += hv * m[i];
                    ssp[j] += hv * hv * m[i];
                }
            cntp += (m[0] + m[1] + m[2] + m[3]) * 0.125f;
        } else {
            // BN1 + relu + mask -> featT in act
            #pragma unroll
            for (int j = 0; j < 8; j++) {
                v4f f;
                #pragma unroll
                for (int i = 0; i < 4; i++) f[i] = fmaxf(a1[i][j] * sc1[j] + sh1[j], 0.f) * m[i];
                st4(&act[wv][(8 * cg + j) * 36 + 4 * pg], f);
            }
            __builtin_amdgcn_wave_barrier();

            // pooled[k] = max_p featT[k][p]; lane handles k = lane
            {
                float mx = 0.f;
                #pragma unroll
                for (int i2 = 0; i2 < 8; i2++) {
                    v4f r = ld4(&act[wv][lane * 36 + 4 * i2]);
                    mx = fmaxf(mx, fmaxf(fmaxf(r[0], r[1]), fmaxf(r[2], r[3])));
                }
                pbuf[wv][lane] = mx;
            }
            __builtin_amdgcn_wave_barrier();

            // qa[j] = sum_k W1p[ch][k] * pooled[k]
            float qa[8] = {0};
            #pragma unroll 8
            for (int k = 0; k < 64; k++) {
                float pv = pbuf[wv][k];
                v4f w0 = ld4(&W1pT[k * 64 + 8 * cg]);
                v4f w1 = ld4(&W1pT[k * 64 + 8 * cg + 4]);
                #pragma unroll
                for (int j = 0; j < 4; j++) { qa[j] += pv * w0[j]; qa[4 + j] += pv * w1[j]; }
            }

            // ---- stage 2: h1 = W1a @ feat + qa  (K=64) ----
            float a2[4][8];
            #pragma unroll
            for (int i = 0; i < 4; i++)
                #pragma unroll
                for (int j = 0; j < 8; j++) a2[i][j] = qa[j];
            #pragma unroll 8
            for (int k = 0; k < 64; k++) {
                v4f av = ld4(&act[wv][k * 36 + 4 * pg]);
                v4f w0 = ld4(&W1aT[k * 64 + 8 * cg]);
                v4f w1 = ld4(&W1aT[k * 64 + 8 * cg + 4]);
                #pragma unroll
                for (int i = 0; i < 4; i++)
                    #pragma unroll
                    for (int j = 0; j < 4; j++) {
                        a2[i][j] += av[i] * w0[j];
                        a2[i][4 + j] += av[i] * w1[j];
                    }
            }

            if constexpr (NSTAGE == 2) {
                #pragma unroll
                for (int i = 0; i < 4; i++)
                    #pragma unroll
                    for (int j = 0; j < 8; j++) {
                        float hv = a2[i][j];
                        sp[j] += hv * m[i];
                        ssp[j] += hv * hv * m[i];
                    }
            } else {
                // BN2 + relu + mask -> gT (reuse act; same-wave LDS is in-order)
                #pragma unroll
                for (int j = 0; j < 8; j++) {
                    v4f g;
                    #pragma unroll
                    for (int i = 0; i < 4; i++) g[i] = fmaxf(a2[i][j] * sc2[j] + sh2[j], 0.f) * m[i];
                    st4(&act[wv][(8 * cg + j) * 36 + 4 * pg], g);
                }
                __builtin_amdgcn_wave_barrier();

                // ---- stage 3: h2 = W2 @ g  (K=64) ----
                float a3[4][8];
                #pragma unroll
                for (int i = 0; i < 4; i++)
                    #pragma unroll
                    for (int j = 0; j < 8; j++) a3[i][j] = 0.f;
                #pragma unroll 8
                for (int k = 0; k < 64; k++) {
                    v4f av = ld4(&act[wv][k * 36 + 4 * pg]);
                    v4f w0 = ld4(&W2T[k * 64 + 8 * cg]);
                    v4f w1 = ld4(&W2T[k * 64 + 8 * cg + 4]);
                    #pragma unroll
                    for (int i = 0; i < 4; i++)
                        #pragma unroll
                        for (int j = 0; j < 4; j++) {
                            a3[i][j] += av[i] * w0[j];
                            a3[i][4 + j] += av[i] * w1[j];
                        }
                }

                if constexpr (!DO_OUT) {
                    #pragma unroll
                    for (int i = 0; i < 4; i++)
                        #pragma unroll
                        for (int j = 0; j < 8; j++) {
                            float hv = a3[i][j];
                            sp[j] += hv * m[i];
                            ssp[j] += hv * hv * m[i];
                        }
                } else {
                    // BN3+relu+mask, max over p -> ovec
                    float pmax[8];
                    #pragma unroll
                    for (int j = 0; j < 8; j++) {
                        float v = 0.f;
                        #pragma unroll
                        for (int i = 0; i < 4; i++)
                            v = fmaxf(v, fmaxf(a3[i][j] * sc3[j] + sh3[j], 0.f) * m[i]);
                        pmax[j] = v;
                    }
                    #pragma unroll
                    for (int j = 0; j < 8; j++) {
                        float v = pmax[j];
                        v = fmaxf(v, __shfl_xor(v, 8));
                        v = fmaxf(v, __shfl_xor(v, 16));
                        v = fmaxf(v, __shfl_xor(v, 32));
                        pmax[j] = v;
                    }
                    if (pg == 0)
                        #pragma unroll
                        for (int j = 0; j < 8; j++) pbuf[wv][8 * cg + j] = pmax[j];
                    __builtin_amdgcn_wave_barrier();

                    // y1 = relu(Wo1 @ ovec + bo1); lane -> ch = lane
                    float y1 = bo1v;
                    #pragma unroll 8
                    for (int k = 0; k < 64; k++) y1 += Wo1T[k * 64 + lane] * pbuf[wv][k];
                    y1 = fmaxf(y1, 0.f);
                    pbuf[wv][lane] = y1;   // after all reads issued (in-order per wave)
                    __builtin_amdgcn_wave_barrier();

                    // y = Wo2 @ y1 + bo2; lane -> o = lane, lane+64
                    float o0 = bo2a, o1 = bo2b;
                    #pragma unroll 8
                    for (int k = 0; k < 64; k++) {
                        float yv = pbuf[wv][k];
                        o0 += Wo2T[k * 128 + lane] * yv;
                        o1 += Wo2T[k * 128 + 64 + lane] * yv;
                    }
                    unsigned long long bl = __ballot(mv > 0.5f);
                    float vf = bl ? 1.f : 0.f;
                    out[(size_t)bn * 128 + lane] = o0 * vf;
                    out[(size_t)bn * 128 + 64 + lane] = o1 * vf;
                }
            }
        }
    }

    // ---- stats reduction + atomics (stats kernels only) ----
    if constexpr (!DO_OUT) {
        #pragma unroll
        for (int j = 0; j < 8; j++) {
            float v = sp[j];
            v += __shfl_xor(v, 8); v += __shfl_xor(v, 16); v += __shfl_xor(v, 32);
            sp[j] = v;
            float w = ssp[j];
            w += __shfl_xor(w, 8); w += __shfl_xor(w, 16); w += __shfl_xor(w, 32);
            ssp[j] = w;
        }
        if (pg == 0)
            #pragma unroll
            for (int j = 0; j < 8; j++) { red_s[wv][8 * cg + j] = sp[j]; red_ss[wv][8 * cg + j] = ssp[j]; }
        if constexpr (NSTAGE == 1) {
            float c = cntp;
            for (int d = 1; d < 64; d <<= 1) c += __shfl_xor(c, d);
            if (lane == 0) red_c[wv] = c;
        }
        __syncthreads();
        if (t < 64) {
            const int base = (NSTAGE - 1) * 128;
            float s4 = red_s[0][t] + red_s[1][t] + red_s[2][t] + red_s[3][t];
            float q4 = red_ss[0][t] + red_ss[1][t] + red_ss[2][t] + red_ss[3][t];
            atomicAdd(&S[base + t], s4);
            atomicAdd(&S[base + 64 + t], q4);
        }
        if (NSTAGE == 1 && t == 0)
            atomicAdd(&S[384], red_c[0] + red_c[1] + red_c[2] + red_c[3]);
    }
}

extern "C" void kernel_launch(void* const* d_in, const int* in_sizes, int n_in,
                              void* d_out, int out_size, void* d_ws, size_t ws_size,
                              hipStream_t stream) {
    const float* poly = (const float*)d_in[0];
    const int*   mask = (const int*)d_in[1];
    const float* Wpre = (const float*)d_in[2];
    const float* gpre = (const float*)d_in[3];
    const float* bpre = (const float*)d_in[4];
    const float* W1   = (const float*)d_in[5];
    const float* g1   = (const float*)d_in[6];
    const float* b1   = (const float*)d_in[7];
    const float* W2   = (const float*)d_in[8];
    const float* g2   = (const float*)d_in[9];
    const float* b2   = (const float*)d_in[10];
    const float* Wo1  = (const float*)d_in[11];
    const float* bo1  = (const float*)d_in[12];
    const float* Wo2  = (const float*)d_in[13];
    const float* bo2  = (const float*)d_in[14];

    float* S = (float*)d_ws;
    float* out = (float*)d_out;

    hipMemsetAsync(S, 0, 512 * sizeof(float), stream);
    pipe_k<1, false><<<NBLK, 256, 0, stream>>>(poly, mask, Wpre, W1, W2, Wo1, bo1, Wo2, bo2, S, out);
    k_finalize<<<1, 64, 0, stream>>>(gpre, bpre, S, 0);
    pipe_k<2, false><<<NBLK, 256, 0, stream>>>(poly, mask, Wpre, W1, W2, Wo1, bo1, Wo2, bo2, S, out);
    k_finalize<<<1, 64, 0, stream>>>(g1, b1, S, 1);
    pipe_k<3, false><<<NBLK, 256, 0, stream>>>(poly, mask, Wpre, W1, W2, Wo1, bo1, Wo2, bo2, S, out);
    k_finalize<<<1, 64, 0, stream>>>(g2, b2, S, 2);
    pipe_k<3, true><<<NBLK, 256, 0, stream>>>(poly, mask, Wpre, W1, W2, Wo1, bo1, Wo2, bo2, S, out);
}

// Round 8
// 538.312 us; speedup vs baseline: 3.4845x; 2.1253x over previous
//
#include <hip/hip_runtime.h>

#define BN_TOT 24576   // B*N
#define EPS_ 1e-5f
#define NBLK 2048
#define TOTW (NBLK * 4)   // 8192 waves; 24576/8192 = exactly 3 polylines per wave

typedef float v4f __attribute__((ext_vector_type(4)));

__device__ __forceinline__ v4f ld4(const float* p) { return *(const v4f*)p; }
__device__ __forceinline__ void st4(float* p, v4f v) { *(v4f*)p = v; }

// Workspace S (floats):
// [0..63] sum1 [64..127] sumsq1 [128..191] sum2 [192..255] sumsq2
// [256..319] sum3 [320..383] sumsq3 [384] cnt
// [512+L*128 .. +63] scaleL, [+64 .. +127] shiftL  (L=0,1,2)
// H buffer (big-ws path) at byte offset 8192: [bn][p][ch] fp32, 201.3 MB

__global__ void k_finalize(const float* __restrict__ g, const float* __restrict__ b,
                           float* __restrict__ S, int layer) {
    int c = threadIdx.x;
    if (c < 64) {
        float cnt = fmaxf(S[384], 1.f);
        float mean = S[layer * 128 + c] / cnt;
        float var = fmaxf(S[layer * 128 + 64 + c] / cnt - mean * mean, 0.f);
        float sc = g[c] * rsqrtf(var + EPS_);
        float sh = b[c] - mean * sc;
        S[512 + layer * 128 + c] = sc;
        S[512 + layer * 128 + 64 + c] = sh;
    }
}

// ---- shared device helpers -------------------------------------------------
// lane = pg*8+cg; tile = points 4pg..4pg+3  x  channels 8cg..8cg+7.
// act: per-wave 64x32 fp32, row ch stride 32, chunk c stored at (c ^ (ch>>3)).
//   writes: addr%32 = 4*(pg^cg)  -> conflict-free
//   reads:  addr%32 = 4*(pg^(k>>3)) -> conflict-free

__device__ __forceinline__ void mm_acc(float a[4][8], v4f av, v4f w0, v4f w1) {
    #pragma unroll
    for (int i = 0; i < 4; i++) {
        #pragma unroll
        for (int j = 0; j < 4; j++) {
            a[i][j] += av[i] * w0[j];
            a[i][4 + j] += av[i] * w1[j];
        }
    }
}

__device__ __forceinline__ void tzero(float a[4][8]) {
    #pragma unroll
    for (int i = 0; i < 4; i++)
        #pragma unroll
        for (int j = 0; j < 8; j++) a[i][j] = 0.f;
}

__device__ __forceinline__ void load_x(const float* xg, float* xTw, int lane) {
    for (int e = lane; e < 288; e += 64) {
        float v = xg[e];
        int p = e / 9, c = e - 9 * p;
        xTw[c * 36 + p] = v;
    }
}

__device__ __forceinline__ void stage1(const float* xTw, const float* WpT,
                                       int pg, int cg, float a1[4][8]) {
    tzero(a1);
    #pragma unroll
    for (int k = 0; k < 9; k++) {
        v4f av = ld4(xTw + k * 36 + 4 * pg);
        v4f w0 = ld4(WpT + k * 64 + 8 * cg);
        v4f w1 = ld4(WpT + k * 64 + 8 * cg + 4);
        mm_acc(a1, av, w0, w1);
    }
}

__device__ __forceinline__ void gemv64(const float* actw, const float* WT,
                                       int pg, int cg, float a[4][8]) {
    #pragma unroll 8
    for (int k = 0; k < 64; k++) {
        v4f av = ld4(actw + k * 32 + 4 * (pg ^ (k >> 3)));
        v4f w0 = ld4(WT + k * 64 + 8 * cg);
        v4f w1 = ld4(WT + k * 64 + 8 * cg + 4);
        mm_acc(a, av, w0, w1);
    }
}

// BN+relu+mask -> act (swizzled) and keep f in regs
__device__ __forceinline__ void bn_store_act(float* actw, const float a[4][8],
                                             const float* sc, const float* sh,
                                             const float m[4], int pg, int cg,
                                             float f[4][8]) {
    #pragma unroll
    for (int j = 0; j < 8; j++) {
        v4f v;
        #pragma unroll
        for (int i = 0; i < 4; i++) {
            float x = fmaxf(a[i][j] * sc[j] + sh[j], 0.f) * m[i];
            v[i] = x; f[i][j] = x;
        }
        st4(actw + (8 * cg + j) * 32 + 4 * (pg ^ cg), v);
    }
}

// pooled via registers+shuffles -> pmax[j] holds pooled[8cg+j] in ALL lanes
__device__ __forceinline__ void pool_reduce(const float f[4][8], float pmax[8]) {
    #pragma unroll
    for (int j = 0; j < 8; j++) {
        float v = fmaxf(fmaxf(f[0][j], f[1][j]), fmaxf(f[2][j], f[3][j]));
        v = fmaxf(v, __shfl_xor(v, 8));
        v = fmaxf(v, __shfl_xor(v, 16));
        v = fmaxf(v, __shfl_xor(v, 32));
        pmax[j] = v;
    }
}

// qa[j] = sum_k W1p[8cg+j][k]*pooled[k], W1p staged in LDS as [k*64+ch]
__device__ __forceinline__ void qa_lds(const float pmax[8], const float* W1pT,
                                       int cg, float qa[8]) {
    #pragma unroll
    for (int j = 0; j < 8; j++) qa[j] = 0.f;
    #pragma unroll
    for (int k = 0; k < 64; k++) {
        float pv = __shfl(pmax[k & 7], k >> 3);   // pooled[k]
        v4f w0 = ld4(W1pT + k * 64 + 8 * cg);
        v4f w1 = ld4(W1pT + k * 64 + 8 * cg + 4);
        #pragma unroll
        for (int j = 0; j < 4; j++) { qa[j] += pv * w0[j]; qa[4 + j] += pv * w1[j]; }
    }
}

// qa reading W1p straight from global (L1-cached), pooled via LDS pbuf
__device__ __forceinline__ void qa_glob(const float pmax[8], const float* W1,
                                        float* pbufw, int pg, int cg, float qa[8]) {
    if (pg == 0)
        #pragma unroll
        for (int j = 0; j < 8; j++) pbufw[8 * cg + j] = pmax[j];
    __builtin_amdgcn_wave_barrier();
    #pragma unroll
    for (int j = 0; j < 8; j++) qa[j] = 0.f;
    #pragma unroll 4
    for (int kk = 0; kk < 16; kk++) {
        float p0 = pbufw[4 * kk], p1 = pbufw[4 * kk + 1];
        float p2 = pbufw[4 * kk + 2], p3 = pbufw[4 * kk + 3];
        #pragma unroll
        for (int j = 0; j < 8; j++) {
            v4f w = ld4(W1 + (8 * cg + j) * 128 + 64 + 4 * kk);
            qa[j] += w[0] * p0 + w[1] * p1 + w[2] * p2 + w[3] * p3;
        }
    }
}

__device__ __forceinline__ void stats_acc(const float a[4][8], const float m[4],
                                          float sp[8], float ssp[8]) {
    #pragma unroll
    for (int i = 0; i < 4; i++)
        #pragma unroll
        for (int j = 0; j < 8; j++) {
            float hv = a[i][j] * m[i];
            sp[j] += hv; ssp[j] += hv * a[i][j];
        }
}

__device__ __forceinline__ void stats_flush(float sp[8], float ssp[8],
                                            float (*red_s)[64], float (*red_ss)[64],
                                            float* S, int base, int t, int wv,
                                            int pg, int cg) {
    #pragma unroll
    for (int j = 0; j < 8; j++) {
        float v = sp[j];
        v += __shfl_xor(v, 8); v += __shfl_xor(v, 16); v += __shfl_xor(v, 32);
        sp[j] = v;
        float w = ssp[j];
        w += __shfl_xor(w, 8); w += __shfl_xor(w, 16); w += __shfl_xor(w, 32);
        ssp[j] = w;
    }
    if (pg == 0)
        #pragma unroll
        for (int j = 0; j < 8; j++) { red_s[wv][8 * cg + j] = sp[j]; red_ss[wv][8 * cg + j] = ssp[j]; }
    __syncthreads();
    if (t < 64) {
        atomicAdd(&S[base + t], red_s[0][t] + red_s[1][t] + red_s[2][t] + red_s[3][t]);
        atomicAdd(&S[base + 64 + t], red_ss[0][t] + red_ss[1][t] + red_ss[2][t] + red_ss[3][t]);
    }
}

// ---- pass 1: stats over h_pre (LDS ~9.6 KB -> full occupancy) -------------
__global__ __launch_bounds__(256) void k_stats1(const float* __restrict__ poly,
                                                const int* __restrict__ mask,
                                                const float* __restrict__ Wpre,
                                                float* __restrict__ S) {
    __shared__ __align__(16) float WpT[576];
    __shared__ __align__(16) float xT[4][324];
    __shared__ float red_s[4][64], red_ss[4][64], red_c[4];
    const int t = threadIdx.x, wv = t >> 6, lane = t & 63;
    const int pg = lane >> 3, cg = lane & 7;
    for (int i = t; i < 576; i += 256) { int c = i >> 6, ch = i & 63; WpT[i] = Wpre[ch * 9 + c]; }
    __syncthreads();
    float sp[8] = {0}, ssp[8] = {0}, cntp = 0.f;
    const int wgid = blockIdx.x * 4 + wv;
    for (int bn = wgid; bn < BN_TOT; bn += TOTW) {
        float mv = (lane < 32 && mask[bn * 32 + lane] != 0) ? 1.f : 0.f;
        float m[4];
        #pragma unroll
        for (int i = 0; i < 4; i++) m[i] = __shfl(mv, 4 * pg + i);
        load_x(poly + (size_t)bn * 288, xT[wv], lane);
        __builtin_amdgcn_wave_barrier();
        float a1[4][8];
        stage1(xT[wv], WpT, pg, cg, a1);
        stats_acc(a1, m, sp, ssp);
        cntp += (m[0] + m[1] + m[2] + m[3]) * 0.125f;
        __builtin_amdgcn_wave_barrier();   // xT reuse next iter
    }
    {
        float c = cntp;
        for (int d = 1; d < 64; d <<= 1) c += __shfl_xor(c, d);
        if (lane == 0) red_c[wv] = c;
    }
    stats_flush(sp, ssp, red_s, red_ss, S, 0, t, wv, pg, cg);
    if (t == 0) atomicAdd(&S[384], red_c[0] + red_c[1] + red_c[2] + red_c[3]);
}

// ---- pass 2: stats over h1 (optionally store h1 to H) ----------------------
template<bool STORE>
__global__ __launch_bounds__(256) void k_stats2(const float* __restrict__ poly,
                                                const int* __restrict__ mask,
                                                const float* __restrict__ Wpre,
                                                const float* __restrict__ W1,
                                                float* __restrict__ S,
                                                float* __restrict__ H) {
    __shared__ __align__(16) float WpT[576];
    __shared__ __align__(16) float W1aT[4096];
    __shared__ __align__(16) float W1pT[4096];
    __shared__ __align__(16) float act[4][2048];
    __shared__ __align__(16) float xT[4][324];
    __shared__ float red_s[4][64], red_ss[4][64];
    const int t = threadIdx.x, wv = t >> 6, lane = t & 63;
    const int pg = lane >> 3, cg = lane & 7;
    for (int i = t; i < 576; i += 256) { int c = i >> 6, ch = i & 63; WpT[i] = Wpre[ch * 9 + c]; }
    for (int i = t; i < 4096; i += 256) {
        int k = i >> 6, ch = i & 63;
        W1aT[i] = W1[ch * 128 + k];
        W1pT[i] = W1[ch * 128 + 64 + k];
    }
    __syncthreads();
    float sc1[8], sh1[8];
    #pragma unroll
    for (int j = 0; j < 8; j++) { sc1[j] = S[512 + 8 * cg + j]; sh1[j] = S[576 + 8 * cg + j]; }
    float sp[8] = {0}, ssp[8] = {0};
    const int wgid = blockIdx.x * 4 + wv;
    for (int bn = wgid; bn < BN_TOT; bn += TOTW) {
        float mv = (lane < 32 && mask[bn * 32 + lane] != 0) ? 1.f : 0.f;
        float m[4];
        #pragma unroll
        for (int i = 0; i < 4; i++) m[i] = __shfl(mv, 4 * pg + i);
        load_x(poly + (size_t)bn * 288, xT[wv], lane);
        __builtin_amdgcn_wave_barrier();
        float a1[4][8], f[4][8];
        stage1(xT[wv], WpT, pg, cg, a1);
        bn_store_act(act[wv], a1, sc1, sh1, m, pg, cg, f);
        float pmax[8], qa[8];
        pool_reduce(f, pmax);
        qa_lds(pmax, W1pT, cg, qa);
        __builtin_amdgcn_wave_barrier();
        float a2[4][8];
        #pragma unroll
        for (int i = 0; i < 4; i++)
            #pragma unroll
            for (int j = 0; j < 8; j++) a2[i][j] = qa[j];
        gemv64(act[wv], W1aT, pg, cg, a2);
        stats_acc(a2, m, sp, ssp);
        if constexpr (STORE) {
            float* Hb = H + (size_t)bn * 2048;
            #pragma unroll
            for (int i = 0; i < 4; i++) {
                v4f lo, hi;
                #pragma unroll
                for (int j = 0; j < 4; j++) { lo[j] = a2[i][j]; hi[j] = a2[i][4 + j]; }
                st4(Hb + (4 * pg + i) * 64 + 8 * cg, lo);
                st4(Hb + (4 * pg + i) * 64 + 8 * cg + 4, hi);
            }
        }
        __builtin_amdgcn_wave_barrier();
    }
    stats_flush(sp, ssp, red_s, red_ss, S, 128, t, wv, pg, cg);
}

// ---- pass 3 (big ws): load h1 -> g -> h2, stats3, store h2 in place --------
__global__ __launch_bounds__(256) void k_stats3_load(const int* __restrict__ mask,
                                                     const float* __restrict__ W2,
                                                     float* __restrict__ S,
                                                     float* __restrict__ H) {
    __shared__ __align__(16) float W2T[4096];
    __shared__ __align__(16) float act[4][2048];
    __shared__ float red_s[4][64], red_ss[4][64];
    const int t = threadIdx.x, wv = t >> 6, lane = t & 63;
    const int pg = lane >> 3, cg = lane & 7;
    for (int i = t; i < 4096; i += 256) { int k = i >> 6, ch = i & 63; W2T[i] = W2[ch * 64 + k]; }
    __syncthreads();
    const int ch0 = 4 * (lane & 15);
    v4f sc2v = ld4(S + 640 + ch0), sh2v = ld4(S + 704 + ch0);
    float sp[8] = {0}, ssp[8] = {0};
    const int wgid = blockIdx.x * 4 + wv;
    for (int bn = wgid; bn < BN_TOT; bn += TOTW) {
        float mv = (lane < 32 && mask[bn * 32 + lane] != 0) ? 1.f : 0.f;
        float m[4];
        #pragma unroll
        for (int i = 0; i < 4; i++) m[i] = __shfl(mv, 4 * pg + i);
        float* Hb = H + (size_t)bn * 2048;
        #pragma unroll
        for (int r = 0; r < 8; r++) {
            int E = r * 256 + lane * 4;
            int p = E >> 6;                 // = r*4 + (lane>>4)
            v4f h = ld4(Hb + E);
            float mp = __shfl(mv, p);
            #pragma unroll
            for (int q = 0; q < 4; q++) {
                float g = fmaxf(h[q] * sc2v[q] + sh2v[q], 0.f) * mp;
                int ch = ch0 + q;
                act[wv][ch * 32 + 4 * ((p >> 2) ^ (ch >> 3)) + (p & 3)] = g;
            }
        }
        __builtin_amdgcn_wave_barrier();
        float a3[4][8];
        tzero(a3);
        gemv64(act[wv], W2T, pg, cg, a3);
        stats_acc(a3, m, sp, ssp);
        #pragma unroll
        for (int i = 0; i < 4; i++) {
            v4f lo, hi;
            #pragma unroll
            for (int j = 0; j < 4; j++) { lo[j] = a3[i][j]; hi[j] = a3[i][4 + j]; }
            st4(Hb + (4 * pg + i) * 64 + 8 * cg, lo);
            st4(Hb + (4 * pg + i) * 64 + 8 * cg + 4, hi);
        }
        __builtin_amdgcn_wave_barrier();
    }
    stats_flush(sp, ssp, red_s, red_ss, S, 256, t, wv, pg, cg);
}

// ---- pass 4 (big ws): load h2 -> BN3 -> pool -> out MLP --------------------
__global__ __launch_bounds__(256) void k_out_load(const int* __restrict__ mask,
                                                  const float* __restrict__ Wo1,
                                                  const float* __restrict__ bo1,
                                                  const float* __restrict__ Wo2,
                                                  const float* __restrict__ bo2,
                                                  const float* __restrict__ S,
                                                  const float* __restrict__ H,
                                                  float* __restrict__ out) {
    __shared__ __align__(16) float Wo1T[4096];
    __shared__ __align__(16) float Wo2T[8192];
    __shared__ float pbuf[4][64];
    const int t = threadIdx.x, wv = t >> 6, lane = t & 63;
    for (int i = t; i < 4096; i += 256) { int k = i >> 6, ch = i & 63; Wo1T[i] = Wo1[ch * 64 + k]; }
    for (int i = t; i < 8192; i += 256) { int k = i >> 7, o = i & 127; Wo2T[i] = Wo2[o * 64 + k]; }
    __syncthreads();
    float sc3 = S[768 + lane], sh3 = S[832 + lane];
    float bo1v = bo1[lane], bo2a = bo2[lane], bo2b = bo2[64 + lane];
    const int wgid = blockIdx.x * 4 + wv;
    for (int bn = wgid; bn < BN_TOT; bn += TOTW) {
        float mv = (lane < 32 && mask[bn * 32 + lane] != 0) ? 1.f : 0.f;
        float vf = __ballot(mv > 0.5f) ? 1.f : 0.f;
        const float* Hb = H + (size_t)bn * 2048;
        float mx = 0.f;
        #pragma unroll 8
        for (int p = 0; p < 32; p++) {
            float h = Hb[p * 64 + lane];
            float mp = __shfl(mv, p);
            mx = fmaxf(mx, fmaxf(h * sc3 + sh3, 0.f) * mp);
        }
        pbuf[wv][lane] = mx;
        __builtin_amdgcn_wave_barrier();
        float y1 = bo1v;
        #pragma unroll 8
        for (int k = 0; k < 64; k++) y1 += Wo1T[k * 64 + lane] * pbuf[wv][k];
        y1 = fmaxf(y1, 0.f);
        pbuf[wv][lane] = y1;
        __builtin_amdgcn_wave_barrier();
        float o0 = bo2a, o1 = bo2b;
        #pragma unroll 8
        for (int k = 0; k < 64; k++) {
            float yv = pbuf[wv][k];
            o0 += Wo2T[k * 128 + lane] * yv;
            o1 += Wo2T[k * 128 + 64 + lane] * yv;
        }
        out[(size_t)bn * 128 + lane] = o0 * vf;
        out[(size_t)bn * 128 + 64 + lane] = o1 * vf;
        __builtin_amdgcn_wave_barrier();
    }
}

// ---- fallback (small ws): recompute passes 3/4 -----------------------------
template<bool DO_OUT>
__global__ __launch_bounds__(256) void k_rec34(const float* __restrict__ poly,
                                               const int* __restrict__ mask,
                                               const float* __restrict__ Wpre,
                                               const float* __restrict__ W1,
                                               const float* __restrict__ W2,
                                               const float* __restrict__ Wo1,
                                               const float* __restrict__ bo1,
                                               const float* __restrict__ Wo2,
                                               const float* __restrict__ bo2,
                                               float* __restrict__ S,
                                               float* __restrict__ out) {
    __shared__ __align__(16) float WpT[576];
    __shared__ __align__(16) float W1aT[4096];
    __shared__ __align__(16) float W2T[4096];
    __shared__ __align__(16) float act[4][2048];
    __shared__ __align__(16) float xT[4][324];
    __shared__ float pbuf[4][64];
    __shared__ float red_s[4][64], red_ss[4][64];
    const int t = threadIdx.x, wv = t >> 6, lane = t & 63;
    const int pg = lane >> 3, cg = lane & 7;
    for (int i = t; i < 576; i += 256) { int c = i >> 6, ch = i & 63; WpT[i] = Wpre[ch * 9 + c]; }
    for (int i = t; i < 4096; i += 256) {
        int k = i >> 6, ch = i & 63;
        W1aT[i] = W1[ch * 128 + k];
        W2T[i] = W2[ch * 64 + k];
    }
    __syncthreads();
    float sc1[8], sh1[8], sc2[8], sh2[8], sc3[8], sh3[8];
    #pragma unroll
    for (int j = 0; j < 8; j++) {
        sc1[j] = S[512 + 8 * cg + j]; sh1[j] = S[576 + 8 * cg + j];
        sc2[j] = S[640 + 8 * cg + j]; sh2[j] = S[704 + 8 * cg + j];
    }
    if constexpr (DO_OUT)
        #pragma unroll
        for (int j = 0; j < 8; j++) { sc3[j] = S[768 + 8 * cg + j]; sh3[j] = S[832 + 8 * cg + j]; }
    float bo1v = 0.f, bo2a = 0.f, bo2b = 0.f;
    if constexpr (DO_OUT) { bo1v = bo1[lane]; bo2a = bo2[lane]; bo2b = bo2[64 + lane]; }
    float sp[8] = {0}, ssp[8] = {0};
    const int wgid = blockIdx.x * 4 + wv;
    for (int bn = wgid; bn < BN_TOT; bn += TOTW) {
        float mv = (lane < 32 && mask[bn * 32 + lane] != 0) ? 1.f : 0.f;
        float m[4];
        #pragma unroll
        for (int i = 0; i < 4; i++) m[i] = __shfl(mv, 4 * pg + i);
        load_x(poly + (size_t)bn * 288, xT[wv], lane);
        __builtin_amdgcn_wave_barrier();
        float a1[4][8], f[4][8];
        stage1(xT[wv], WpT, pg, cg, a1);
        bn_store_act(act[wv], a1, sc1, sh1, m, pg, cg, f);
        float pmax[8], qa[8];
        pool_reduce(f, pmax);
        qa_glob(pmax, W1, pbuf[wv], pg, cg, qa);
        __builtin_amdgcn_wave_barrier();
        float a2[4][8];
        #pragma unroll
        for (int i = 0; i < 4; i++)
            #pragma unroll
            for (int j = 0; j < 8; j++) a2[i][j] = qa[j];
        gemv64(act[wv], W1aT, pg, cg, a2);
        // BN2 -> g into act (same-wave in-order LDS)
        __builtin_amdgcn_wave_barrier();
        bn_store_act(act[wv], a2, sc2, sh2, m, pg, cg, f);
        __builtin_amdgcn_wave_barrier();
        float a3[4][8];
        tzero(a3);
        gemv64(act[wv], W2T, pg, cg, a3);
        if constexpr (!DO_OUT) {
            stats_acc(a3, m, sp, ssp);
        } else {
            float px[8];
            #pragma unroll
            for (int j = 0; j < 8; j++) {
                float v = 0.f;
                #pragma unroll
                for (int i = 0; i < 4; i++)
                    v = fmaxf(v, fmaxf(a3[i][j] * sc3[j] + sh3[j], 0.f) * m[i]);
                px[j] = v;
            }
            #pragma unroll
            for (int j = 0; j < 8; j++) {
                float v = px[j];
                v = fmaxf(v, __shfl_xor(v, 8));
                v = fmaxf(v, __shfl_xor(v, 16));
                v = fmaxf(v, __shfl_xor(v, 32));
                px[j] = v;
            }
            if (pg == 0)
                #pragma unroll
                for (int j = 0; j < 8; j++) pbuf[wv][8 * cg + j] = px[j];
            __builtin_amdgcn_wave_barrier();
            float y1 = bo1v;
            #pragma unroll 4
            for (int kk = 0; kk < 16; kk++) {
                v4f w = ld4(Wo1 + lane * 64 + 4 * kk);
                y1 += w[0] * pbuf[wv][4 * kk] + w[1] * pbuf[wv][4 * kk + 1]
                    + w[2] * pbuf[wv][4 * kk + 2] + w[3] * pbuf[wv][4 * kk + 3];
            }
            y1 = fmaxf(y1, 0.f);
            pbuf[wv][lane] = y1;
            __builtin_amdgcn_wave_barrier();
            float o0 = bo2a, o1 = bo2b;
            #pragma unroll 4
            for (int kk = 0; kk < 16; kk++) {
                v4f w0 = ld4(Wo2 + lane * 64 + 4 * kk);
                v4f w1 = ld4(Wo2 + (64 + lane) * 64 + 4 * kk);
                float p0 = pbuf[wv][4 * kk], p1 = pbuf[wv][4 * kk + 1];
                float p2 = pbuf[wv][4 * kk + 2], p3 = pbuf[wv][4 * kk + 3];
                o0 += w0[0] * p0 + w0[1] * p1 + w0[2] * p2 + w0[3] * p3;
                o1 += w1[0] * p0 + w1[1] * p1 + w1[2] * p2 + w1[3] * p3;
            }
            float vf = __ballot(mv > 0.5f) ? 1.f : 0.f;
            out[(size_t)bn * 128 + lane] = o0 * vf;
            out[(size_t)bn * 128 + 64 + lane] = o1 * vf;
        }
        __builtin_amdgcn_wave_barrier();
    }
    if constexpr (!DO_OUT)
        stats_flush(sp, ssp, red_s, red_ss, S, 256, t, wv, pg, cg);
}

extern "C" void kernel_launch(void* const* d_in, const int* in_sizes, int n_in,
                              void* d_out, int out_size, void* d_ws, size_t ws_size,
                              hipStream_t stream) {
    const float* poly = (const float*)d_in[0];
    const int*   mask = (const int*)d_in[1];
    const float* Wpre = (const float*)d_in[2];
    const float* gpre = (const float*)d_in[3];
    const float* bpre = (const float*)d_in[4];
    const float* W1   = (const float*)d_in[5];
    const float* g1   = (const float*)d_in[6];
    const float* b1   = (const float*)d_in[7];
    const float* W2   = (const float*)d_in[8];
    const float* g2   = (const float*)d_in[9];
    const float* b2   = (const float*)d_in[10];
    const float* Wo1  = (const float*)d_in[11];
    const float* bo1  = (const float*)d_in[12];
    const float* Wo2  = (const float*)d_in[13];
    const float* bo2  = (const float*)d_in[14];

    float* S = (float*)d_ws;
    float* H = (float*)((char*)d_ws + 8192);
    float* out = (float*)d_out;

    const size_t needWS = 8192 + (size_t)BN_TOT * 2048 * sizeof(float);  // ~201.3 MB

    hipMemsetAsync(S, 0, 512 * sizeof(float), stream);
    k_stats1<<<NBLK, 256, 0, stream>>>(poly, mask, Wpre, S);
    k_finalize<<<1, 64, 0, stream>>>(gpre, bpre, S, 0);
    if (ws_size >= needWS) {
        k_stats2<true><<<NBLK, 256, 0, stream>>>(poly, mask, Wpre, W1, S, H);
        k_finalize<<<1, 64, 0, stream>>>(g1, b1, S, 1);
        k_stats3_load<<<NBLK, 256, 0, stream>>>(mask, W2, S, H);
        k_finalize<<<1, 64, 0, stream>>>(g2, b2, S, 2);
        k_out_load<<<NBLK, 256, 0, stream>>>(mask, Wo1, bo1, Wo2, bo2, S, H, out);
    } else {
        k_stats2<false><<<NBLK, 256, 0, stream>>>(poly, mask, Wpre, W1, S, H);
        k_finalize<<<1, 64, 0, stream>>>(g1, b1, S, 1);
        k_rec34<false><<<NBLK, 256, 0, stream>>>(poly, mask, Wpre, W1, W2, Wo1, bo1, Wo2, bo2, S, out);
        k_finalize<<<1, 64, 0, stream>>>(g2, b2, S, 2);
        k_rec34<true><<<NBLK, 256, 0, stream>>>(poly, mask, Wpre, W1, W2, Wo1, bo1, Wo2, bo2, S, out);
    }
}